// Round 19
// baseline (693.932 us; speedup 1.0000x reference)
//
#include <hip/hip_runtime.h>
#include <hip/hip_bf16.h>

#define N_NODES 100000
#define N_EDGES 1600000
#define IN_DIM  500
#define HID     128
#define KDIM    512   // HID * (DEG+1)
#define NB      782   // ceil(N_NODES/128) buckets
#define BCAP    4096  // bucket capacity (expected 2046, >20 sigma headroom)

#define NG_GEMM 1563  // gemm_xw blocks
#define NG_BIN  6250  // bin blocks

typedef __attribute__((ext_vector_type(8))) short bf16x8;
typedef __attribute__((ext_vector_type(4))) float f32x4;

__device__ inline short f2bf(float x) {
    union { float f; unsigned u; } v; v.f = x;
    unsigned r = (v.u + 0x7FFFu + ((v.u >> 16) & 1u)) >> 16;  // RNE
    return (short)r;
}
__device__ inline float bf_lo(unsigned u) { union { unsigned u; float f; } v; v.u = u << 16; return v.f; }
__device__ inline float bf_hi(unsigned u) { union { unsigned u; float f; } v; v.u = u & 0xFFFF0000u; return v.f; }

// Chebyshev basis from 2 packed bf16 features -> 8 bf16 A-fragment
__device__ inline bf16x8 cheb_frag(unsigned v) {
    float hx[2] = {bf_lo(v), bf_hi(v)};
    short t[8];
#pragma unroll
    for (int q = 0; q < 2; q++) {
        float xx = fminf(fmaxf(hx[q], -15.f), 15.f);
        float e  = __expf(2.f * xx);
        float tt = (e - 1.f) / (e + 1.f);     // tanh
        float T2 = 2.f * tt * tt - 1.f;
        float T3 = 2.f * tt * T2 - tt;
        t[q * 4 + 0] = (short)0x3F80;         // bf16(1.0)
        t[q * 4 + 1] = f2bf(tt);
        t[q * 4 + 2] = f2bf(T2);
        t[q * 4 + 3] = f2bf(T3);
    }
    return *(bf16x8*)&t[0];
}

// ---------------------------------------------------------------------------
// Merged repacks, launched BEFORE prep (prep's gemm reads Wmat).
// ---------------------------------------------------------------------------
__global__ __launch_bounds__(256) void repack_all(const float* __restrict__ cheb,
                                                  const float* __restrict__ W,
                                                  const float* __restrict__ Wout,
                                                  unsigned short* __restrict__ Bmat,
                                                  unsigned short* __restrict__ Wmat,
                                                  unsigned short* __restrict__ C2W) {
    const int b = blockIdx.x;
    if (b < 256) {
        int idx = b * 256 + threadIdx.x;       // < 128*512
        int o = idx >> 9;
        int k = idx & 511;
        int i = k >> 2;
        int d = k & 3;
        Bmat[idx] = (unsigned short)f2bf(cheb[i * 512 + o * 4 + d]);
    } else if (b < 512) {
        int idx = (b - 256) * 256 + threadIdx.x;
        int o = idx >> 9;
        int k = idx & 511;
        Wmat[idx] = (k < IN_DIM) ? (unsigned short)f2bf(W[k * HID + o]) : 0;
    } else {
        int idx = (b - 512) * 256 + threadIdx.x;   // < 16*512
        int o16 = idx >> 9;
        int k   = idx & 511;
        const float* cb = cheb + 65536 + (k >> 2) * 512 + (k & 3);
        float s = 0.f;
#pragma unroll 4
        for (int o = 0; o < 128; o++) s += cb[o * 4] * Wout[o * 16 + o16];
        C2W[o16 * 512 + k] = (unsigned short)f2bf(s);
    }
}

// ---------------------------------------------------------------------------
// PREP super-kernel: blocks [0,NG_GEMM) run gemm_xw (h = x @ W_in); remainder
// runs edge binning. Disjoint outputs (hA vs bbuf=hB + bcnt).
// gemm A-path REBUILT for stream contiguity (r18 falsified latency-bound
// theory): full 64-row x panel staged to LDS (64KB) via ROW-CONTIGUOUS 1KB
// wave reads; XOR-swizzled layout; K-loop barrier-free with A from LDS and
// B direct from L2-resident Wmat. LDS caps occupancy at 2 blocks/CU.
// ---------------------------------------------------------------------------
__global__ __launch_bounds__(256, 2) void prep_kernel(const float* __restrict__ x,
                                                      const int* __restrict__ ei,
                                                      const unsigned short* __restrict__ Wmat,
                                                      unsigned short* __restrict__ hA,
                                                      int* __restrict__ bcnt,
                                                      unsigned* __restrict__ bbuf) {
    __shared__ __align__(16) short As[64][512];   // 64 KB (gemm blocks only)
    const int tid = threadIdx.x;

    if (blockIdx.x < NG_GEMM) {
        const int lane = tid & 63;
        const int wave = tid >> 6;
        const int quad = lane >> 4;
        const int l16  = lane & 15;
        const int n0   = blockIdx.x * 64;

        // ---- stage A panel: row-contiguous 1KB wave reads, swizzled ------
#pragma unroll
        for (int r16 = 0; r16 < 16; r16++) {
            const int slot = wave * 16 + r16;
            int row = n0 + slot; if (row >= N_NODES) row = N_NODES - 1;
            const float4* __restrict__ xr4 = (const float4*)(x + (long)row * IN_DIM);
            const int xr = (r16 & 7) << 3;        // swizzle (units: shorts)
#pragma unroll
            for (int i = 0; i < 2; i++) {
                int idx = i * 64 + lane;          // float4 index 0..127
                float4 v;
                if (idx < 125) v = xr4[idx];      // 500 floats = 125 float4
                else { v.x = 0.f; v.y = 0.f; v.z = 0.f; v.w = 0.f; }
                short t[4];
                t[0] = f2bf(v.x); t[1] = f2bf(v.y); t[2] = f2bf(v.z); t[3] = f2bf(v.w);
                *(unsigned long long*)&As[slot][(idx * 4) ^ xr] = *(unsigned long long*)&t[0];
            }
        }

        f32x4 acc[8];
#pragma unroll
        for (int nt = 0; nt < 8; nt++)
#pragma unroll
            for (int r = 0; r < 4; r++) acc[nt][r] = 0.f;

        __syncthreads();     // A panel ready — the ONLY barrier

        const int arow = wave * 16 + l16;
        const int axr  = (l16 & 7) << 3;
#pragma unroll
        for (int kt = 0; kt < 16; kt++) {
            bf16x8 a = *(const bf16x8*)&As[arow][(kt * 32 + quad * 8) ^ axr];
#pragma unroll
            for (int nt = 0; nt < 8; nt++) {
                bf16x8 b = *(const bf16x8*)&Wmat[(nt * 16 + l16) * 512 + kt * 32 + quad * 8];
                acc[nt] = __builtin_amdgcn_mfma_f32_16x16x32_bf16(a, b, acc[nt], 0, 0, 0);
            }
        }

        int mrow = n0 + wave * 16 + quad * 4;
#pragma unroll
        for (int r = 0; r < 4; r++) {
            int n = mrow + r;
            if (n < N_NODES) {
#pragma unroll
                for (int nt = 0; nt < 8; nt++)
                    hA[(long)n * HID + nt * 16 + l16] = (unsigned short)f2bf(acc[nt][r]);
            }
        }
    } else {
        // ---- bin: bucket each edge by row>>7 ------------------------------
        int e = (blockIdx.x - NG_GEMM) * 256 + tid;
        if (e < N_EDGES) {
            int r = ei[e];
            int c = ei[N_EDGES + e];
            int b = r >> 7;
            int p = atomicAdd(&bcnt[b * 16], 1);   // stride 64 B: spread L2 slices
            if (p < BCAP) bbuf[b * BCAP + p] = ((unsigned)(r & 127) << 17) | (unsigned)c;
        }
    }
}

// ---------------------------------------------------------------------------
// place: per-bucket local histogram + scan; bucket's global base claimed via
// ONE atomic ticket (no bscan). Rows get row_start+row_cnt.
// ---------------------------------------------------------------------------
__global__ __launch_bounds__(256) void place_kernel(const unsigned* __restrict__ buf,
                                                    const int* __restrict__ bcnt,
                                                    int* __restrict__ gctr,
                                                    int* __restrict__ row_start,
                                                    int* __restrict__ row_cnt,
                                                    int* __restrict__ col_sorted) {
    __shared__ int hist[128];
    __shared__ int scan[128];
    __shared__ int cur[128];
    __shared__ int base_s;
    const int b = blockIdx.x, tid = threadIdx.x;
    int cnt = bcnt[b * 16]; if (cnt > BCAP) cnt = BCAP;
    if (tid < 128) hist[tid] = 0;
    __syncthreads();
    for (int i = tid; i < cnt; i += 256)
        atomicAdd(&hist[buf[b * BCAP + i] >> 17], 1);
    __syncthreads();
    if (tid < 128) scan[tid] = hist[tid];
    __syncthreads();
    for (int off = 1; off < 128; off <<= 1) {
        int t = (tid < 128 && tid >= off) ? scan[tid - off] : 0;
        __syncthreads();
        if (tid < 128) scan[tid] += t;
        __syncthreads();
    }
    if (tid == 0) base_s = atomicAdd(gctr, scan[127]);   // ticket for this bucket
    __syncthreads();
    const int base = base_s;
    if (tid < 128) {
        int excl = scan[tid] - hist[tid] + base;
        cur[tid] = excl;
        int r = b * 128 + tid;
        if (r < N_NODES) { row_start[r] = excl; row_cnt[r] = hist[tid]; }
    }
    __syncthreads();
    for (int i = tid; i < cnt; i += 256) {
        unsigned u = buf[b * BCAP + i];
        int rl = (int)(u >> 17);
        int c  = (int)(u & 0x1FFFFu);
        int pos = atomicAdd(&cur[rl], 1);
        col_sorted[pos] = c;
    }
}

// ---------------------------------------------------------------------------
// MFMA GEMM 2 (layer 0): out = Basis(h) @ C1  [N x 512]@[512 x 128]
// A via upfront register preload + per-kt basis. B dbuf'd.
// ---------------------------------------------------------------------------
__global__ __launch_bounds__(256, 4) void cheb_gemm(const unsigned short* __restrict__ h,
                                                    const unsigned short* __restrict__ Bmat,
                                                    unsigned short* __restrict__ out) {
    __shared__ __align__(16) short Bs[2][128][40];
    const int tid  = threadIdx.x;
    const int lane = tid & 63;
    const int wave = tid >> 6;
    const int quad = lane >> 4;
    const int l16  = lane & 15;
    const int n0   = blockIdx.x * 64;
    const int br   = tid >> 1;
    const int bh   = tid & 1;

    int row = n0 + wave * 16 + l16; if (row >= N_NODES) row = N_NODES - 1;
    const unsigned short* __restrict__ hrow = h + (long)row * HID;

    unsigned hreg[16];
#pragma unroll
    for (int kt = 0; kt < 16; kt++)
        hreg[kt] = *(const unsigned*)(hrow + kt * 8 + quad * 2);

    f32x4 acc[8];
#pragma unroll
    for (int nt = 0; nt < 8; nt++)
#pragma unroll
        for (int r = 0; r < 4; r++) acc[nt][r] = 0.f;

    auto loadB = [&](int kt, bf16x8 (&w)[2]) {
        w[0] = *(const bf16x8*)&Bmat[br * 512 + kt * 32 + bh * 16];
        w[1] = *(const bf16x8*)&Bmat[br * 512 + kt * 32 + bh * 16 + 8];
    };
    auto storeB = [&](int buf, const bf16x8 (&w)[2]) {
        *(bf16x8*)&Bs[buf][br][bh * 16]     = w[0];
        *(bf16x8*)&Bs[buf][br][bh * 16 + 8] = w[1];
    };
    auto mfmaTile = [&](int buf, int kt) {
        bf16x8 a = cheb_frag(hreg[kt]);
#pragma unroll
        for (int nt = 0; nt < 8; nt++) {
            bf16x8 b = *(const bf16x8*)&Bs[buf][nt * 16 + l16][quad * 8];
            acc[nt] = __builtin_amdgcn_mfma_f32_16x16x32_bf16(a, b, acc[nt], 0, 0, 0);
        }
    };

    bf16x8 wa[2], wb[2];
    loadB(0, wa);
    for (int kt = 0; kt < 16; kt += 2) {
        storeB(0, wa);
        loadB(kt + 1, wb);
        __syncthreads();
        mfmaTile(0, kt);
        storeB(1, wb);
        if (kt + 2 < 16) loadB(kt + 2, wa);
        __syncthreads();
        mfmaTile(1, kt + 1);
    }

    {
        int mrow = n0 + wave * 16 + quad * 4;
#pragma unroll
        for (int r = 0; r < 4; r++) {
            int n = mrow + r;
            if (n < N_NODES) {
#pragma unroll
                for (int nt = 0; nt < 8; nt++)
                    out[(long)n * HID + nt * 16 + l16] = (unsigned short)f2bf(acc[nt][r]);
            }
        }
    }
}

// ---------------------------------------------------------------------------
// MFMA GEMM 3 (layer 1 + W_out folded): z = Basis(h) @ C2W  [N x 512]@[512 x 16]
// B LDS-resident; A in registers; one barrier total.
// ---------------------------------------------------------------------------
__global__ __launch_bounds__(256, 4) void cheb16_gemm(const unsigned short* __restrict__ h,
                                                      const unsigned short* __restrict__ C2W,
                                                      float* __restrict__ z) {
    __shared__ __align__(16) short Bs16[16][520];
    const int tid  = threadIdx.x;
    const int lane = tid & 63;
    const int wave = tid >> 6;
    const int quad = lane >> 4;
    const int l16  = lane & 15;
    const int n0   = blockIdx.x * 64;

    {
        int o16 = tid >> 4;
        int seg = tid & 15;
        *(bf16x8*)&Bs16[o16][seg * 32]      = *(const bf16x8*)&C2W[o16 * 512 + seg * 32];
        *(bf16x8*)&Bs16[o16][seg * 32 + 8]  = *(const bf16x8*)&C2W[o16 * 512 + seg * 32 + 8];
        *(bf16x8*)&Bs16[o16][seg * 32 + 16] = *(const bf16x8*)&C2W[o16 * 512 + seg * 32 + 16];
        *(bf16x8*)&Bs16[o16][seg * 32 + 24] = *(const bf16x8*)&C2W[o16 * 512 + seg * 32 + 24];
    }

    int row = n0 + wave * 16 + l16; if (row >= N_NODES) row = N_NODES - 1;
    const unsigned short* __restrict__ hrow = h + (long)row * HID;

    unsigned hreg[16];
#pragma unroll
    for (int kt = 0; kt < 16; kt++)
        hreg[kt] = *(const unsigned*)(hrow + kt * 8 + quad * 2);

    f32x4 acc;
#pragma unroll
    for (int r = 0; r < 4; r++) acc[r] = 0.f;

    __syncthreads();   // B ready; the only barrier

#pragma unroll
    for (int kt = 0; kt < 16; kt++) {
        bf16x8 a = cheb_frag(hreg[kt]);
        bf16x8 b = *(const bf16x8*)&Bs16[l16][kt * 32 + quad * 8];
        acc = __builtin_amdgcn_mfma_f32_16x16x32_bf16(a, b, acc, 0, 0, 0);
    }

    {
        int mrow = n0 + wave * 16 + quad * 4;
#pragma unroll
        for (int r = 0; r < 4; r++) {
            int n = mrow + r;
            if (n < N_NODES) z[n * 16 + l16] = acc[r];
        }
    }
}

// ---------------------------------------------------------------------------
// SpMM gather (128-wide bf16, ROW-major h): wave/row; 16 lanes x uint4 per
// edge, 4 edges/instr, unrolled x2. Row bounds via row_start + row_cnt.
// ---------------------------------------------------------------------------
__global__ __launch_bounds__(256) void spmm_gather(const int* __restrict__ row_start,
                                                   const int* __restrict__ row_cnt,
                                                   const int* __restrict__ col_sorted,
                                                   const unsigned short* __restrict__ h,
                                                   unsigned short* __restrict__ out) {
    const int wid  = (blockIdx.x * 256 + threadIdx.x) >> 6;   // row
    const int lane = threadIdx.x & 63;
    const int sub  = lane >> 4;        // edge slot 0..3
    const int fl   = lane & 15;        // 16-byte feature slice 0..15
    if (wid >= N_NODES) return;
    const int s = row_start[wid];
    const int e = s + row_cnt[wid];
    const uint4* __restrict__ h4 = (const uint4*)h;   // one row = 16 uint4

    float a[8], b[8];
#pragma unroll
    for (int q = 0; q < 8; q++) { a[q] = 0.f; b[q] = 0.f; }

    int j = s;
    for (; j + 8 <= e; j += 8) {
        int c0 = col_sorted[j + sub];
        int c1 = col_sorted[j + 4 + sub];
        uint4 u0 = h4[c0 * 16 + fl];
        uint4 u1 = h4[c1 * 16 + fl];
        a[0] += bf_lo(u0.x); a[1] += bf_hi(u0.x);
        a[2] += bf_lo(u0.y); a[3] += bf_hi(u0.y);
        a[4] += bf_lo(u0.z); a[5] += bf_hi(u0.z);
        a[6] += bf_lo(u0.w); a[7] += bf_hi(u0.w);
        b[0] += bf_lo(u1.x); b[1] += bf_hi(u1.x);
        b[2] += bf_lo(u1.y); b[3] += bf_hi(u1.y);
        b[4] += bf_lo(u1.z); b[5] += bf_hi(u1.z);
        b[6] += bf_lo(u1.w); b[7] += bf_hi(u1.w);
    }
    for (; j < e; j += 4) {
        int idx = j + sub;
        float m = (idx < e) ? 1.f : 0.f;
        int ci = (idx < e) ? idx : (e - 1);
        int c = col_sorted[ci];
        uint4 u = h4[c * 16 + fl];
        a[0] = fmaf(m, bf_lo(u.x), a[0]); a[1] = fmaf(m, bf_hi(u.x), a[1]);
        a[2] = fmaf(m, bf_lo(u.y), a[2]); a[3] = fmaf(m, bf_hi(u.y), a[3]);
        a[4] = fmaf(m, bf_lo(u.z), a[4]); a[5] = fmaf(m, bf_hi(u.z), a[5]);
        a[6] = fmaf(m, bf_lo(u.w), a[6]); a[7] = fmaf(m, bf_hi(u.w), a[7]);
    }
#pragma unroll
    for (int q = 0; q < 8; q++) a[q] += b[q];
#pragma unroll
    for (int q = 0; q < 8; q++) {
        a[q] += __shfl_xor(a[q], 16);
        a[q] += __shfl_xor(a[q], 32);
    }
    if (sub == 0) {
        unsigned w0 = (unsigned)(unsigned short)f2bf(a[0]) | ((unsigned)(unsigned short)f2bf(a[1]) << 16);
        unsigned w1 = (unsigned)(unsigned short)f2bf(a[2]) | ((unsigned)(unsigned short)f2bf(a[3]) << 16);
        unsigned w2 = (unsigned)(unsigned short)f2bf(a[4]) | ((unsigned)(unsigned short)f2bf(a[5]) << 16);
        unsigned w3 = (unsigned)(unsigned short)f2bf(a[6]) | ((unsigned)(unsigned short)f2bf(a[7]) << 16);
        uint4 pw; pw.x = w0; pw.y = w1; pw.z = w2; pw.w = w3;
        ((uint4*)out)[wid * 16 + fl] = pw;
    }
}

// ---------------------------------------------------------------------------
// Final spmm (16-wide f32) + log_softmax fused; bounds via row_start+row_cnt.
// ---------------------------------------------------------------------------
__global__ __launch_bounds__(256) void spmm_out(const int* __restrict__ row_start,
                                                const int* __restrict__ row_cnt,
                                                const int* __restrict__ col_sorted,
                                                const float* __restrict__ z,
                                                float* __restrict__ out) {
    const int wid  = (blockIdx.x * 256 + threadIdx.x) >> 6;
    const int lane = threadIdx.x & 63;
    const int sub  = lane >> 4;
    const int fl   = lane & 15;
    if (wid >= N_NODES) return;
    const int s = row_start[wid];
    const int e = s + row_cnt[wid];

    float a0 = 0.f, a1 = 0.f;
    int j = s;
    for (; j + 8 <= e; j += 8) {
        int c0 = col_sorted[j + sub];
        int c1 = col_sorted[j + 4 + sub];
        a0 += z[c0 * 16 + fl];
        a1 += z[c1 * 16 + fl];
    }
    for (; j < e; j += 4) {
        int idx = j + sub;
        float m = (idx < e) ? 1.f : 0.f;
        int ci = (idx < e) ? idx : (e - 1);
        a0 = fmaf(m, z[col_sorted[ci] * 16 + fl], a0);
    }
    float v = a0 + a1;
    v += __shfl_xor(v, 16);
    v += __shfl_xor(v, 32);
    float mx = v;
#pragma unroll
    for (int m = 8; m >= 1; m >>= 1) mx = fmaxf(mx, __shfl_xor(mx, m));
    float ex = expf(v - mx);
    float se = ex;
#pragma unroll
    for (int m = 8; m >= 1; m >>= 1) se += __shfl_xor(se, m);
    if (sub == 0) out[wid * 16 + fl] = v - mx - logf(se);
}

// ---------------------------------------------------------------------------

extern "C" void kernel_launch(void* const* d_in, const int* in_sizes, int n_in,
                              void* d_out, int out_size, void* d_ws, size_t ws_size,
                              hipStream_t stream) {
    const float* x     = (const float*)d_in[0];
    const int*   ei    = (const int*)d_in[1];
    const float* W_in  = (const float*)d_in[2];
    const float* cheb  = (const float*)d_in[3];
    const float* W_out = (const float*)d_in[4];
    float* out = (float*)d_out;

    char* p = (char*)d_ws;
    unsigned short* hA   = (unsigned short*)p; p += (size_t)N_NODES * HID * 2;   // 25.6 MB
    unsigned short* hB   = (unsigned short*)p; p += (size_t)N_NODES * HID * 2;   // 25.6 MB
    int*   col_sorted    = (int*)p;            p += (size_t)N_EDGES * 4;         // 6.4 MB
    unsigned short* Bmat = (unsigned short*)p; p += (size_t)HID * KDIM * 2;      // 128 KB (layer-0)
    unsigned short* Wmat = (unsigned short*)p; p += (size_t)HID * KDIM * 2;      // 128 KB
    unsigned short* C2W  = (unsigned short*)p; p += (size_t)16 * KDIM * 2;       // 16 KB
    float* zbuf          = (float*)p;          p += (size_t)N_NODES * 16 * 4;    // 6.4 MB
    int*   row_start     = (int*)p;            p += (size_t)N_NODES * 4;         // 400 KB
    int*   row_cnt       = (int*)p;            p += (size_t)N_NODES * 4;         // 400 KB
    int*   bcnt          = (int*)p;            p += (size_t)(NB * 16 + 16) * 4;  // 50 KB + gctr slot

    int* gctr = bcnt + NB * 16;   // zeroed by the same memset

    // bucket buffer aliases hB (dead until spmm1 writes it; prep's gemm
    // section writes hA only, so bin ∥ gemm is safe)
    unsigned* bbuf = (unsigned*)hB;

    const int nblk_prep = NG_GEMM + NG_BIN;            // 7813
    const int nblk_gemm = (N_NODES + 63) / 64;         // 1563
    const int nblk_spmm = (N_NODES + 3) / 4;           // 25000

    hipMemsetAsync(bcnt, 0, (size_t)(NB * 16 + 16) * 4, stream);

    repack_all<<<544, 256, 0, stream>>>(cheb, W_in, W_out, Bmat, Wmat, C2W);

    // gemm_xw ∥ bin in one launch (disjoint outputs)
    prep_kernel<<<nblk_prep, 256, 0, stream>>>(x, ei, Wmat, hA, bcnt, bbuf);
    place_kernel<<<NB, 256, 0, stream>>>(bbuf, bcnt, gctr, row_start, row_cnt, col_sorted);

    spmm_gather<<<nblk_spmm, 256, 0, stream>>>(row_start, row_cnt, col_sorted, hA, hB);

    cheb_gemm<<<nblk_gemm, 256, 0, stream>>>(hB, Bmat, hA);                    // layer 0
    spmm_gather<<<nblk_spmm, 256, 0, stream>>>(row_start, row_cnt, col_sorted, hA, hB);

    cheb16_gemm<<<nblk_gemm, 256, 0, stream>>>(hB, C2W, zbuf);                 // layer 1 + W_out
    spmm_out<<<nblk_spmm, 256, 0, stream>>>(row_start, row_cnt, col_sorted, zbuf, out); // spmm + lsm
}

// Round 20
// 678.453 us; speedup vs baseline: 1.0228x; 1.0228x over previous
//
#include <hip/hip_runtime.h>
#include <hip/hip_bf16.h>

#define N_NODES 100000
#define N_EDGES 1600000
#define IN_DIM  500
#define HID     128
#define KDIM    512   // HID * (DEG+1)
#define NB      782   // ceil(N_NODES/128) buckets
#define BCAP    4096  // bucket capacity (expected 2046, >20 sigma headroom)

#define NG_GEMM 1563  // gemm_xw blocks
#define NG_BIN  6250  // bin blocks

typedef __attribute__((ext_vector_type(8))) short bf16x8;
typedef __attribute__((ext_vector_type(4))) float f32x4;

__device__ inline short f2bf(float x) {
    union { float f; unsigned u; } v; v.f = x;
    unsigned r = (v.u + 0x7FFFu + ((v.u >> 16) & 1u)) >> 16;  // RNE
    return (short)r;
}
__device__ inline float bf_lo(unsigned u) { union { unsigned u; float f; } v; v.u = u << 16; return v.f; }
__device__ inline float bf_hi(unsigned u) { union { unsigned u; float f; } v; v.u = u & 0xFFFF0000u; return v.f; }

// Chebyshev basis from 2 packed bf16 features -> 8 bf16 A-fragment
__device__ inline bf16x8 cheb_frag(unsigned v) {
    float hx[2] = {bf_lo(v), bf_hi(v)};
    short t[8];
#pragma unroll
    for (int q = 0; q < 2; q++) {
        float xx = fminf(fmaxf(hx[q], -15.f), 15.f);
        float e  = __expf(2.f * xx);
        float tt = (e - 1.f) / (e + 1.f);     // tanh
        float T2 = 2.f * tt * tt - 1.f;
        float T3 = 2.f * tt * T2 - tt;
        t[q * 4 + 0] = (short)0x3F80;         // bf16(1.0)
        t[q * 4 + 1] = f2bf(tt);
        t[q * 4 + 2] = f2bf(T2);
        t[q * 4 + 3] = f2bf(T3);
    }
    return *(bf16x8*)&t[0];
}

// ---------------------------------------------------------------------------
// Merged repacks, launched BEFORE prep (prep's gemm reads Wmat).
// ---------------------------------------------------------------------------
__global__ __launch_bounds__(256) void repack_all(const float* __restrict__ cheb,
                                                  const float* __restrict__ W,
                                                  const float* __restrict__ Wout,
                                                  unsigned short* __restrict__ Bmat,
                                                  unsigned short* __restrict__ Wmat,
                                                  unsigned short* __restrict__ C2W) {
    const int b = blockIdx.x;
    if (b < 256) {
        int idx = b * 256 + threadIdx.x;       // < 128*512
        int o = idx >> 9;
        int k = idx & 511;
        int i = k >> 2;
        int d = k & 3;
        Bmat[idx] = (unsigned short)f2bf(cheb[i * 512 + o * 4 + d]);
    } else if (b < 512) {
        int idx = (b - 256) * 256 + threadIdx.x;
        int o = idx >> 9;
        int k = idx & 511;
        Wmat[idx] = (k < IN_DIM) ? (unsigned short)f2bf(W[k * HID + o]) : 0;
    } else {
        int idx = (b - 512) * 256 + threadIdx.x;   // < 16*512
        int o16 = idx >> 9;
        int k   = idx & 511;
        const float* cb = cheb + 65536 + (k >> 2) * 512 + (k & 3);
        float s = 0.f;
#pragma unroll 4
        for (int o = 0; o < 128; o++) s += cb[o * 4] * Wout[o * 16 + o16];
        C2W[o16 * 512 + k] = (unsigned short)f2bf(s);
    }
}

// ---------------------------------------------------------------------------
// PREP super-kernel: blocks [0,NG_GEMM) run gemm_xw (h = x @ W_in); remainder
// runs edge binning. Disjoint outputs (hA vs bbuf=hB + bcnt).
// gemm: ZERO LDS, ZERO BARRIERS (r19 insight: __syncthreads emits
// s_waitcnt vmcnt(0) -> every barrier drained the prefetch ring; r18's
// deeper ring was useless). A = 4-deep global->reg ring; B = direct from
// L2-resident Wmat with 2-slot register dbuf. Loads now stay in flight
// across the whole unrolled K-loop.
// ---------------------------------------------------------------------------
__global__ __launch_bounds__(256, 3) void prep_kernel(const float* __restrict__ x,
                                                      const int* __restrict__ ei,
                                                      const unsigned short* __restrict__ Wmat,
                                                      unsigned short* __restrict__ hA,
                                                      int* __restrict__ bcnt,
                                                      unsigned* __restrict__ bbuf) {
    const int tid = threadIdx.x;

    if (blockIdx.x < NG_GEMM) {
        const int lane = tid & 63;
        const int wave = tid >> 6;
        const int quad = lane >> 4;
        const int l16  = lane & 15;
        const int n0   = blockIdx.x * 64;

        int row = n0 + wave * 16 + l16; if (row >= N_NODES) row = N_NODES - 1;
        const float* __restrict__ xrow = x + (long)row * IN_DIM;

        f32x4 acc[8];
#pragma unroll
        for (int nt = 0; nt < 8; nt++)
#pragma unroll
            for (int r = 0; r < 4; r++) acc[nt][r] = 0.f;

        auto loadA = [&](int kt, float (&v)[8]) {
            const int kb = kt * 32 + quad * 8;
            if (kb + 8 <= IN_DIM) {
                const float4* s4 = (const float4*)(xrow + kb);
                float4 a0 = s4[0], a1 = s4[1];
                v[0]=a0.x; v[1]=a0.y; v[2]=a0.z; v[3]=a0.w;
                v[4]=a1.x; v[5]=a1.y; v[6]=a1.z; v[7]=a1.w;
            } else {
#pragma unroll
                for (int q = 0; q < 8; q++) v[q] = (kb + q < IN_DIM) ? xrow[kb + q] : 0.f;
            }
        };
        auto loadBrow = [&](int kt, bf16x8 (&B)[8]) {
#pragma unroll
            for (int nt = 0; nt < 8; nt++)
                B[nt] = *(const bf16x8*)&Wmat[(nt * 16 + l16) * 512 + kt * 32 + quad * 8];
        };
        auto mfmaRow = [&](const float (&v)[8], const bf16x8 (&B)[8]) {
            short t[8];
#pragma unroll
            for (int q = 0; q < 8; q++) t[q] = f2bf(v[q]);
            bf16x8 a = *(bf16x8*)&t[0];
#pragma unroll
            for (int nt = 0; nt < 8; nt++)
                acc[nt] = __builtin_amdgcn_mfma_f32_16x16x32_bf16(a, B[nt], acc[nt], 0, 0, 0);
        };

        float  A[4][8];               // 4-deep A ring; compile-time indices
        bf16x8 B0[8], B1[8];          // 2-slot B dbuf (static names)
        loadA(0, A[0]);
        loadA(1, A[1]);
        loadBrow(0, B0);
#pragma unroll
        for (int kt = 0; kt < 16; kt += 2) {
            if (kt + 1 < 16) loadBrow(kt + 1, B1);
            if (kt + 2 < 16) loadA(kt + 2, A[(kt + 2) & 3]);
            mfmaRow(A[kt & 3], B0);
            if (kt + 2 < 16) loadBrow(kt + 2, B0);
            if (kt + 3 < 16) loadA(kt + 3, A[(kt + 3) & 3]);
            mfmaRow(A[(kt + 1) & 3], B1);
        }

        int mrow = n0 + wave * 16 + quad * 4;
#pragma unroll
        for (int r = 0; r < 4; r++) {
            int n = mrow + r;
            if (n < N_NODES) {
#pragma unroll
                for (int nt = 0; nt < 8; nt++)
                    hA[(long)n * HID + nt * 16 + l16] = (unsigned short)f2bf(acc[nt][r]);
            }
        }
    } else {
        // ---- bin: bucket each edge by row>>7 ------------------------------
        int e = (blockIdx.x - NG_GEMM) * 256 + tid;
        if (e < N_EDGES) {
            int r = ei[e];
            int c = ei[N_EDGES + e];
            int b = r >> 7;
            int p = atomicAdd(&bcnt[b * 16], 1);   // stride 64 B: spread L2 slices
            if (p < BCAP) bbuf[b * BCAP + p] = ((unsigned)(r & 127) << 17) | (unsigned)c;
        }
    }
}

// ---------------------------------------------------------------------------
// place: per-bucket local histogram + scan; bucket's global base claimed via
// ONE atomic ticket (no bscan). Rows get row_start+row_cnt.
// ---------------------------------------------------------------------------
__global__ __launch_bounds__(256) void place_kernel(const unsigned* __restrict__ buf,
                                                    const int* __restrict__ bcnt,
                                                    int* __restrict__ gctr,
                                                    int* __restrict__ row_start,
                                                    int* __restrict__ row_cnt,
                                                    int* __restrict__ col_sorted) {
    __shared__ int hist[128];
    __shared__ int scan[128];
    __shared__ int cur[128];
    __shared__ int base_s;
    const int b = blockIdx.x, tid = threadIdx.x;
    int cnt = bcnt[b * 16]; if (cnt > BCAP) cnt = BCAP;
    if (tid < 128) hist[tid] = 0;
    __syncthreads();
    for (int i = tid; i < cnt; i += 256)
        atomicAdd(&hist[buf[b * BCAP + i] >> 17], 1);
    __syncthreads();
    if (tid < 128) scan[tid] = hist[tid];
    __syncthreads();
    for (int off = 1; off < 128; off <<= 1) {
        int t = (tid < 128 && tid >= off) ? scan[tid - off] : 0;
        __syncthreads();
        if (tid < 128) scan[tid] += t;
        __syncthreads();
    }
    if (tid == 0) base_s = atomicAdd(gctr, scan[127]);   // ticket for this bucket
    __syncthreads();
    const int base = base_s;
    if (tid < 128) {
        int excl = scan[tid] - hist[tid] + base;
        cur[tid] = excl;
        int r = b * 128 + tid;
        if (r < N_NODES) { row_start[r] = excl; row_cnt[r] = hist[tid]; }
    }
    __syncthreads();
    for (int i = tid; i < cnt; i += 256) {
        unsigned u = buf[b * BCAP + i];
        int rl = (int)(u >> 17);
        int c  = (int)(u & 0x1FFFFu);
        int pos = atomicAdd(&cur[rl], 1);
        col_sorted[pos] = c;
    }
}

// ---------------------------------------------------------------------------
// MFMA GEMM 2 (layer 0): out = Basis(h) @ C1  [N x 512]@[512 x 128]
// A via upfront register preload + per-kt basis. B dbuf'd.
// ---------------------------------------------------------------------------
__global__ __launch_bounds__(256, 4) void cheb_gemm(const unsigned short* __restrict__ h,
                                                    const unsigned short* __restrict__ Bmat,
                                                    unsigned short* __restrict__ out) {
    __shared__ __align__(16) short Bs[2][128][40];
    const int tid  = threadIdx.x;
    const int lane = tid & 63;
    const int wave = tid >> 6;
    const int quad = lane >> 4;
    const int l16  = lane & 15;
    const int n0   = blockIdx.x * 64;
    const int br   = tid >> 1;
    const int bh   = tid & 1;

    int row = n0 + wave * 16 + l16; if (row >= N_NODES) row = N_NODES - 1;
    const unsigned short* __restrict__ hrow = h + (long)row * HID;

    unsigned hreg[16];
#pragma unroll
    for (int kt = 0; kt < 16; kt++)
        hreg[kt] = *(const unsigned*)(hrow + kt * 8 + quad * 2);

    f32x4 acc[8];
#pragma unroll
    for (int nt = 0; nt < 8; nt++)
#pragma unroll
        for (int r = 0; r < 4; r++) acc[nt][r] = 0.f;

    auto loadB = [&](int kt, bf16x8 (&w)[2]) {
        w[0] = *(const bf16x8*)&Bmat[br * 512 + kt * 32 + bh * 16];
        w[1] = *(const bf16x8*)&Bmat[br * 512 + kt * 32 + bh * 16 + 8];
    };
    auto storeB = [&](int buf, const bf16x8 (&w)[2]) {
        *(bf16x8*)&Bs[buf][br][bh * 16]     = w[0];
        *(bf16x8*)&Bs[buf][br][bh * 16 + 8] = w[1];
    };
    auto mfmaTile = [&](int buf, int kt) {
        bf16x8 a = cheb_frag(hreg[kt]);
#pragma unroll
        for (int nt = 0; nt < 8; nt++) {
            bf16x8 b = *(const bf16x8*)&Bs[buf][nt * 16 + l16][quad * 8];
            acc[nt] = __builtin_amdgcn_mfma_f32_16x16x32_bf16(a, b, acc[nt], 0, 0, 0);
        }
    };

    bf16x8 wa[2], wb[2];
    loadB(0, wa);
    for (int kt = 0; kt < 16; kt += 2) {
        storeB(0, wa);
        loadB(kt + 1, wb);
        __syncthreads();
        mfmaTile(0, kt);
        storeB(1, wb);
        if (kt + 2 < 16) loadB(kt + 2, wa);
        __syncthreads();
        mfmaTile(1, kt + 1);
    }

    {
        int mrow = n0 + wave * 16 + quad * 4;
#pragma unroll
        for (int r = 0; r < 4; r++) {
            int n = mrow + r;
            if (n < N_NODES) {
#pragma unroll
                for (int nt = 0; nt < 8; nt++)
                    out[(long)n * HID + nt * 16 + l16] = (unsigned short)f2bf(acc[nt][r]);
            }
        }
    }
}

// ---------------------------------------------------------------------------
// MFMA GEMM 3 (layer 1 + W_out folded): z = Basis(h) @ C2W  [N x 512]@[512 x 16]
// B LDS-resident; A in registers; one barrier total.
// ---------------------------------------------------------------------------
__global__ __launch_bounds__(256, 4) void cheb16_gemm(const unsigned short* __restrict__ h,
                                                      const unsigned short* __restrict__ C2W,
                                                      float* __restrict__ z) {
    __shared__ __align__(16) short Bs16[16][520];
    const int tid  = threadIdx.x;
    const int lane = tid & 63;
    const int wave = tid >> 6;
    const int quad = lane >> 4;
    const int l16  = lane & 15;
    const int n0   = blockIdx.x * 64;

    {
        int o16 = tid >> 4;
        int seg = tid & 15;
        *(bf16x8*)&Bs16[o16][seg * 32]      = *(const bf16x8*)&C2W[o16 * 512 + seg * 32];
        *(bf16x8*)&Bs16[o16][seg * 32 + 8]  = *(const bf16x8*)&C2W[o16 * 512 + seg * 32 + 8];
        *(bf16x8*)&Bs16[o16][seg * 32 + 16] = *(const bf16x8*)&C2W[o16 * 512 + seg * 32 + 16];
        *(bf16x8*)&Bs16[o16][seg * 32 + 24] = *(const bf16x8*)&C2W[o16 * 512 + seg * 32 + 24];
    }

    int row = n0 + wave * 16 + l16; if (row >= N_NODES) row = N_NODES - 1;
    const unsigned short* __restrict__ hrow = h + (long)row * HID;

    unsigned hreg[16];
#pragma unroll
    for (int kt = 0; kt < 16; kt++)
        hreg[kt] = *(const unsigned*)(hrow + kt * 8 + quad * 2);

    f32x4 acc;
#pragma unroll
    for (int r = 0; r < 4; r++) acc[r] = 0.f;

    __syncthreads();   // B ready; the only barrier

#pragma unroll
    for (int kt = 0; kt < 16; kt++) {
        bf16x8 a = cheb_frag(hreg[kt]);
        bf16x8 b = *(const bf16x8*)&Bs16[l16][kt * 32 + quad * 8];
        acc = __builtin_amdgcn_mfma_f32_16x16x32_bf16(a, b, acc, 0, 0, 0);
    }

    {
        int mrow = n0 + wave * 16 + quad * 4;
#pragma unroll
        for (int r = 0; r < 4; r++) {
            int n = mrow + r;
            if (n < N_NODES) z[n * 16 + l16] = acc[r];
        }
    }
}

// ---------------------------------------------------------------------------
// SpMM gather (128-wide bf16, ROW-major h): wave/row; 16 lanes x uint4 per
// edge, 4 edges/instr, unrolled x2. Row bounds via row_start + row_cnt.
// ---------------------------------------------------------------------------
__global__ __launch_bounds__(256) void spmm_gather(const int* __restrict__ row_start,
                                                   const int* __restrict__ row_cnt,
                                                   const int* __restrict__ col_sorted,
                                                   const unsigned short* __restrict__ h,
                                                   unsigned short* __restrict__ out) {
    const int wid  = (blockIdx.x * 256 + threadIdx.x) >> 6;   // row
    const int lane = threadIdx.x & 63;
    const int sub  = lane >> 4;        // edge slot 0..3
    const int fl   = lane & 15;        // 16-byte feature slice 0..15
    if (wid >= N_NODES) return;
    const int s = row_start[wid];
    const int e = s + row_cnt[wid];
    const uint4* __restrict__ h4 = (const uint4*)h;   // one row = 16 uint4

    float a[8], b[8];
#pragma unroll
    for (int q = 0; q < 8; q++) { a[q] = 0.f; b[q] = 0.f; }

    int j = s;
    for (; j + 8 <= e; j += 8) {
        int c0 = col_sorted[j + sub];
        int c1 = col_sorted[j + 4 + sub];
        uint4 u0 = h4[c0 * 16 + fl];
        uint4 u1 = h4[c1 * 16 + fl];
        a[0] += bf_lo(u0.x); a[1] += bf_hi(u0.x);
        a[2] += bf_lo(u0.y); a[3] += bf_hi(u0.y);
        a[4] += bf_lo(u0.z); a[5] += bf_hi(u0.z);
        a[6] += bf_lo(u0.w); a[7] += bf_hi(u0.w);
        b[0] += bf_lo(u1.x); b[1] += bf_hi(u1.x);
        b[2] += bf_lo(u1.y); b[3] += bf_hi(u1.y);
        b[4] += bf_lo(u1.z); b[5] += bf_hi(u1.z);
        b[6] += bf_lo(u1.w); b[7] += bf_hi(u1.w);
    }
    for (; j < e; j += 4) {
        int idx = j + sub;
        float m = (idx < e) ? 1.f : 0.f;
        int ci = (idx < e) ? idx : (e - 1);
        int c = col_sorted[ci];
        uint4 u = h4[c * 16 + fl];
        a[0] = fmaf(m, bf_lo(u.x), a[0]); a[1] = fmaf(m, bf_hi(u.x), a[1]);
        a[2] = fmaf(m, bf_lo(u.y), a[2]); a[3] = fmaf(m, bf_hi(u.y), a[3]);
        a[4] = fmaf(m, bf_lo(u.z), a[4]); a[5] = fmaf(m, bf_hi(u.z), a[5]);
        a[6] = fmaf(m, bf_lo(u.w), a[6]); a[7] = fmaf(m, bf_hi(u.w), a[7]);
    }
#pragma unroll
    for (int q = 0; q < 8; q++) a[q] += b[q];
#pragma unroll
    for (int q = 0; q < 8; q++) {
        a[q] += __shfl_xor(a[q], 16);
        a[q] += __shfl_xor(a[q], 32);
    }
    if (sub == 0) {
        unsigned w0 = (unsigned)(unsigned short)f2bf(a[0]) | ((unsigned)(unsigned short)f2bf(a[1]) << 16);
        unsigned w1 = (unsigned)(unsigned short)f2bf(a[2]) | ((unsigned)(unsigned short)f2bf(a[3]) << 16);
        unsigned w2 = (unsigned)(unsigned short)f2bf(a[4]) | ((unsigned)(unsigned short)f2bf(a[5]) << 16);
        unsigned w3 = (unsigned)(unsigned short)f2bf(a[6]) | ((unsigned)(unsigned short)f2bf(a[7]) << 16);
        uint4 pw; pw.x = w0; pw.y = w1; pw.z = w2; pw.w = w3;
        ((uint4*)out)[wid * 16 + fl] = pw;
    }
}

// ---------------------------------------------------------------------------
// Final spmm (16-wide f32) + log_softmax fused; bounds via row_start+row_cnt.
// ---------------------------------------------------------------------------
__global__ __launch_bounds__(256) void spmm_out(const int* __restrict__ row_start,
                                                const int* __restrict__ row_cnt,
                                                const int* __restrict__ col_sorted,
                                                const float* __restrict__ z,
                                                float* __restrict__ out) {
    const int wid  = (blockIdx.x * 256 + threadIdx.x) >> 6;
    const int lane = threadIdx.x & 63;
    const int sub  = lane >> 4;
    const int fl   = lane & 15;
    if (wid >= N_NODES) return;
    const int s = row_start[wid];
    const int e = s + row_cnt[wid];

    float a0 = 0.f, a1 = 0.f;
    int j = s;
    for (; j + 8 <= e; j += 8) {
        int c0 = col_sorted[j + sub];
        int c1 = col_sorted[j + 4 + sub];
        a0 += z[c0 * 16 + fl];
        a1 += z[c1 * 16 + fl];
    }
    for (; j < e; j += 4) {
        int idx = j + sub;
        float m = (idx < e) ? 1.f : 0.f;
        int ci = (idx < e) ? idx : (e - 1);
        a0 = fmaf(m, z[col_sorted[ci] * 16 + fl], a0);
    }
    float v = a0 + a1;
    v += __shfl_xor(v, 16);
    v += __shfl_xor(v, 32);
    float mx = v;
#pragma unroll
    for (int m = 8; m >= 1; m >>= 1) mx = fmaxf(mx, __shfl_xor(mx, m));
    float ex = expf(v - mx);
    float se = ex;
#pragma unroll
    for (int m = 8; m >= 1; m >>= 1) se += __shfl_xor(se, m);
    if (sub == 0) out[wid * 16 + fl] = v - mx - logf(se);
}

// ---------------------------------------------------------------------------

extern "C" void kernel_launch(void* const* d_in, const int* in_sizes, int n_in,
                              void* d_out, int out_size, void* d_ws, size_t ws_size,
                              hipStream_t stream) {
    const float* x     = (const float*)d_in[0];
    const int*   ei    = (const int*)d_in[1];
    const float* W_in  = (const float*)d_in[2];
    const float* cheb  = (const float*)d_in[3];
    const float* W_out = (const float*)d_in[4];
    float* out = (float*)d_out;

    char* p = (char*)d_ws;
    unsigned short* hA   = (unsigned short*)p; p += (size_t)N_NODES * HID * 2;   // 25.6 MB
    unsigned short* hB   = (unsigned short*)p; p += (size_t)N_NODES * HID * 2;   // 25.6 MB
    int*   col_sorted    = (int*)p;            p += (size_t)N_EDGES * 4;         // 6.4 MB
    unsigned short* Bmat = (unsigned short*)p; p += (size_t)HID * KDIM * 2;      // 128 KB (layer-0)
    unsigned short* Wmat = (unsigned short*)p; p += (size_t)HID * KDIM * 2;      // 128 KB
    unsigned short* C2W  = (unsigned short*)p; p += (size_t)16 * KDIM * 2;       // 16 KB
    float* zbuf          = (float*)p;          p += (size_t)N_NODES * 16 * 4;    // 6.4 MB
    int*   row_start     = (int*)p;            p += (size_t)N_NODES * 4;         // 400 KB
    int*   row_cnt       = (int*)p;            p += (size_t)N_NODES * 4;         // 400 KB
    int*   bcnt          = (int*)p;            p += (size_t)(NB * 16 + 16) * 4;  // 50 KB + gctr slot

    int* gctr = bcnt + NB * 16;   // zeroed by the same memset

    // bucket buffer aliases hB (dead until spmm1 writes it; prep's gemm
    // section writes hA only, so bin ∥ gemm is safe)
    unsigned* bbuf = (unsigned*)hB;

    const int nblk_prep = NG_GEMM + NG_BIN;            // 7813
    const int nblk_gemm = (N_NODES + 63) / 64;         // 1563
    const int nblk_spmm = (N_NODES + 3) / 4;           // 25000

    hipMemsetAsync(bcnt, 0, (size_t)(NB * 16 + 16) * 4, stream);

    repack_all<<<544, 256, 0, stream>>>(cheb, W_in, W_out, Bmat, Wmat, C2W);

    // gemm_xw ∥ bin in one launch (disjoint outputs)
    prep_kernel<<<nblk_prep, 256, 0, stream>>>(x, ei, Wmat, hA, bcnt, bbuf);
    place_kernel<<<NB, 256, 0, stream>>>(bbuf, bcnt, gctr, row_start, row_cnt, col_sorted);

    spmm_gather<<<nblk_spmm, 256, 0, stream>>>(row_start, row_cnt, col_sorted, hA, hB);

    cheb_gemm<<<nblk_gemm, 256, 0, stream>>>(hB, Bmat, hA);                    // layer 0
    spmm_gather<<<nblk_spmm, 256, 0, stream>>>(row_start, row_cnt, col_sorted, hA, hB);

    cheb16_gemm<<<nblk_gemm, 256, 0, stream>>>(hB, C2W, zbuf);                 // layer 1 + W_out
    spmm_out<<<nblk_spmm, 256, 0, stream>>>(row_start, row_cnt, col_sorted, zbuf, out); // spmm + lsm
}

// Round 21
// 615.027 us; speedup vs baseline: 1.1283x; 1.1031x over previous
//
#include <hip/hip_runtime.h>
#include <hip/hip_bf16.h>

#define N_NODES 100000
#define N_EDGES 1600000
#define IN_DIM  500
#define HID     128
#define KDIM    512   // HID * (DEG+1)
#define NB      782   // ceil(N_NODES/128) buckets
#define BCAP    4096  // bucket capacity (expected 2046, >20 sigma headroom)

#define NG_GEMM 782   // gemm_xw blocks (128-row tiles, 512 threads)
#define NG_BIN  3125  // bin blocks (512 edges each)

typedef __attribute__((ext_vector_type(8))) short bf16x8;
typedef __attribute__((ext_vector_type(4))) float f32x4;

__device__ inline short f2bf(float x) {
    union { float f; unsigned u; } v; v.f = x;
    unsigned r = (v.u + 0x7FFFu + ((v.u >> 16) & 1u)) >> 16;  // RNE
    return (short)r;
}
__device__ inline float bf_lo(unsigned u) { union { unsigned u; float f; } v; v.u = u << 16; return v.f; }
__device__ inline float bf_hi(unsigned u) { union { unsigned u; float f; } v; v.u = u & 0xFFFF0000u; return v.f; }

// Chebyshev basis from 2 packed bf16 features -> 8 bf16 A-fragment
__device__ inline bf16x8 cheb_frag(unsigned v) {
    float hx[2] = {bf_lo(v), bf_hi(v)};
    short t[8];
#pragma unroll
    for (int q = 0; q < 2; q++) {
        float xx = fminf(fmaxf(hx[q], -15.f), 15.f);
        float e  = __expf(2.f * xx);
        float tt = (e - 1.f) / (e + 1.f);     // tanh
        float T2 = 2.f * tt * tt - 1.f;
        float T3 = 2.f * tt * T2 - tt;
        t[q * 4 + 0] = (short)0x3F80;         // bf16(1.0)
        t[q * 4 + 1] = f2bf(tt);
        t[q * 4 + 2] = f2bf(T2);
        t[q * 4 + 3] = f2bf(T3);
    }
    return *(bf16x8*)&t[0];
}

// ---------------------------------------------------------------------------
// Merged repacks, launched BEFORE prep (prep's gemm reads Wmat).
// ---------------------------------------------------------------------------
__global__ __launch_bounds__(256) void repack_all(const float* __restrict__ cheb,
                                                  const float* __restrict__ W,
                                                  const float* __restrict__ Wout,
                                                  unsigned short* __restrict__ Bmat,
                                                  unsigned short* __restrict__ Wmat,
                                                  unsigned short* __restrict__ C2W) {
    const int b = blockIdx.x;
    if (b < 256) {
        int idx = b * 256 + threadIdx.x;       // < 128*512
        int o = idx >> 9;
        int k = idx & 511;
        int i = k >> 2;
        int d = k & 3;
        Bmat[idx] = (unsigned short)f2bf(cheb[i * 512 + o * 4 + d]);
    } else if (b < 512) {
        int idx = (b - 256) * 256 + threadIdx.x;
        int o = idx >> 9;
        int k = idx & 511;
        Wmat[idx] = (k < IN_DIM) ? (unsigned short)f2bf(W[k * HID + o]) : 0;
    } else {
        int idx = (b - 512) * 256 + threadIdx.x;   // < 16*512
        int o16 = idx >> 9;
        int k   = idx & 511;
        const float* cb = cheb + 65536 + (k >> 2) * 512 + (k & 3);
        float s = 0.f;
#pragma unroll 4
        for (int o = 0; o < 128; o++) s += cb[o * 4] * Wout[o * 16 + o16];
        C2W[o16 * 512 + k] = (unsigned short)f2bf(s);
    }
}

// ---------------------------------------------------------------------------
// PREP super-kernel, 512 threads: blocks [0,NG_GEMM) run gemm_xw on 128-row
// tiles (8 waves share ONE 20.5KB B-dbuf); remainder runs edge binning.
// r20 post-mortem: effective x-BW tracks OCCUPANCY (50%->1.33TB/s,
// 30%->0.99, 22%->0.89); per-wave structure changes were all neutral/worse.
// 512-thread blocks allow 4 blocks x 8 waves = 32 waves/CU under the same
// LDS footprint -> double the resident waves feeding the x-stream.
// Per-wave A path identical to r18 (4-deep ring); math bit-identical.
// ---------------------------------------------------------------------------
__global__ __launch_bounds__(512, 2) void prep_kernel(const float* __restrict__ x,
                                                      const int* __restrict__ ei,
                                                      const unsigned short* __restrict__ Wmat,
                                                      unsigned short* __restrict__ hA,
                                                      int* __restrict__ bcnt,
                                                      unsigned* __restrict__ bbuf) {
    __shared__ __align__(16) short Bs[2][128][40];   // 20.5 KB, shared by 8 waves
    const int tid = threadIdx.x;

    if (blockIdx.x < NG_GEMM) {
        const int lane = tid & 63;
        const int wave = tid >> 6;     // 0..7
        const int quad = lane >> 4;
        const int l16  = lane & 15;
        const int n0   = blockIdx.x * 128;
        const int br   = tid >> 2;     // B row 0..127
        const int bh   = tid & 3;      // 8-short segment

        int row = n0 + wave * 16 + l16; if (row >= N_NODES) row = N_NODES - 1;
        const float* __restrict__ xrow = x + (long)row * IN_DIM;

        f32x4 acc[8];
#pragma unroll
        for (int nt = 0; nt < 8; nt++)
#pragma unroll
            for (int r = 0; r < 4; r++) acc[nt][r] = 0.f;

        auto loadA = [&](int kt, float (&v)[8]) {
            const int kb = kt * 32 + quad * 8;
            if (kb + 8 <= IN_DIM) {
                const float4* s4 = (const float4*)(xrow + kb);
                float4 a0 = s4[0], a1 = s4[1];
                v[0]=a0.x; v[1]=a0.y; v[2]=a0.z; v[3]=a0.w;
                v[4]=a1.x; v[5]=a1.y; v[6]=a1.z; v[7]=a1.w;
            } else {
#pragma unroll
                for (int q = 0; q < 8; q++) v[q] = (kb + q < IN_DIM) ? xrow[kb + q] : 0.f;
            }
        };
        auto loadB = [&](int kt, bf16x8& w) {
            w = *(const bf16x8*)&Wmat[br * 512 + kt * 32 + bh * 8];
        };
        auto storeB = [&](int buf, const bf16x8& w) {
            *(bf16x8*)&Bs[buf][br][bh * 8] = w;
        };
        auto mfmaTile = [&](int buf, const float (&v)[8]) {
            short t[8];
#pragma unroll
            for (int q = 0; q < 8; q++) t[q] = f2bf(v[q]);
            bf16x8 a = *(bf16x8*)&t[0];
#pragma unroll
            for (int nt = 0; nt < 8; nt++) {
                bf16x8 b = *(const bf16x8*)&Bs[buf][nt * 16 + l16][quad * 8];
                acc[nt] = __builtin_amdgcn_mfma_f32_16x16x32_bf16(a, b, acc[nt], 0, 0, 0);
            }
        };

        float  A[4][8];               // 4-deep ring; all indices compile-time
        bf16x8 wa, wb;
        loadA(0, A[0]);
        loadA(1, A[1]);
        loadB(0, wa);
#pragma unroll
        for (int kt = 0; kt < 16; kt += 2) {
            storeB(0, wa);
            loadB(kt + 1, wb);
            if (kt + 2 < 16) loadA(kt + 2, A[(kt + 2) & 3]);
            __syncthreads();
            mfmaTile(0, A[kt & 3]);
            storeB(1, wb);
            if (kt + 3 < 16) loadA(kt + 3, A[(kt + 3) & 3]);
            if (kt + 2 < 16) loadB(kt + 2, wa);
            __syncthreads();
            mfmaTile(1, A[(kt + 1) & 3]);
        }

        int mrow = n0 + wave * 16 + quad * 4;
#pragma unroll
        for (int r = 0; r < 4; r++) {
            int n = mrow + r;
            if (n < N_NODES) {
#pragma unroll
                for (int nt = 0; nt < 8; nt++)
                    hA[(long)n * HID + nt * 16 + l16] = (unsigned short)f2bf(acc[nt][r]);
            }
        }
    } else {
        // ---- bin: bucket each edge by row>>7 ------------------------------
        int e = (blockIdx.x - NG_GEMM) * 512 + tid;
        if (e < N_EDGES) {
            int r = ei[e];
            int c = ei[N_EDGES + e];
            int b = r >> 7;
            int p = atomicAdd(&bcnt[b * 16], 1);   // stride 64 B: spread L2 slices
            if (p < BCAP) bbuf[b * BCAP + p] = ((unsigned)(r & 127) << 17) | (unsigned)c;
        }
    }
}

// ---------------------------------------------------------------------------
// place: per-bucket local histogram + scan; bucket's global base claimed via
// ONE atomic ticket (no bscan). Rows get row_start+row_cnt.
// ---------------------------------------------------------------------------
__global__ __launch_bounds__(256) void place_kernel(const unsigned* __restrict__ buf,
                                                    const int* __restrict__ bcnt,
                                                    int* __restrict__ gctr,
                                                    int* __restrict__ row_start,
                                                    int* __restrict__ row_cnt,
                                                    int* __restrict__ col_sorted) {
    __shared__ int hist[128];
    __shared__ int scan[128];
    __shared__ int cur[128];
    __shared__ int base_s;
    const int b = blockIdx.x, tid = threadIdx.x;
    int cnt = bcnt[b * 16]; if (cnt > BCAP) cnt = BCAP;
    if (tid < 128) hist[tid] = 0;
    __syncthreads();
    for (int i = tid; i < cnt; i += 256)
        atomicAdd(&hist[buf[b * BCAP + i] >> 17], 1);
    __syncthreads();
    if (tid < 128) scan[tid] = hist[tid];
    __syncthreads();
    for (int off = 1; off < 128; off <<= 1) {
        int t = (tid < 128 && tid >= off) ? scan[tid - off] : 0;
        __syncthreads();
        if (tid < 128) scan[tid] += t;
        __syncthreads();
    }
    if (tid == 0) base_s = atomicAdd(gctr, scan[127]);   // ticket for this bucket
    __syncthreads();
    const int base = base_s;
    if (tid < 128) {
        int excl = scan[tid] - hist[tid] + base;
        cur[tid] = excl;
        int r = b * 128 + tid;
        if (r < N_NODES) { row_start[r] = excl; row_cnt[r] = hist[tid]; }
    }
    __syncthreads();
    for (int i = tid; i < cnt; i += 256) {
        unsigned u = buf[b * BCAP + i];
        int rl = (int)(u >> 17);
        int c  = (int)(u & 0x1FFFFu);
        int pos = atomicAdd(&cur[rl], 1);
        col_sorted[pos] = c;
    }
}

// ---------------------------------------------------------------------------
// MFMA GEMM 2 (layer 0): out = Basis(h) @ C1  [N x 512]@[512 x 128]
// A via upfront register preload + per-kt basis. B dbuf'd.
// ---------------------------------------------------------------------------
__global__ __launch_bounds__(256, 4) void cheb_gemm(const unsigned short* __restrict__ h,
                                                    const unsigned short* __restrict__ Bmat,
                                                    unsigned short* __restrict__ out) {
    __shared__ __align__(16) short Bs[2][128][40];
    const int tid  = threadIdx.x;
    const int lane = tid & 63;
    const int wave = tid >> 6;
    const int quad = lane >> 4;
    const int l16  = lane & 15;
    const int n0   = blockIdx.x * 64;
    const int br   = tid >> 1;
    const int bh   = tid & 1;

    int row = n0 + wave * 16 + l16; if (row >= N_NODES) row = N_NODES - 1;
    const unsigned short* __restrict__ hrow = h + (long)row * HID;

    unsigned hreg[16];
#pragma unroll
    for (int kt = 0; kt < 16; kt++)
        hreg[kt] = *(const unsigned*)(hrow + kt * 8 + quad * 2);

    f32x4 acc[8];
#pragma unroll
    for (int nt = 0; nt < 8; nt++)
#pragma unroll
        for (int r = 0; r < 4; r++) acc[nt][r] = 0.f;

    auto loadB = [&](int kt, bf16x8 (&w)[2]) {
        w[0] = *(const bf16x8*)&Bmat[br * 512 + kt * 32 + bh * 16];
        w[1] = *(const bf16x8*)&Bmat[br * 512 + kt * 32 + bh * 16 + 8];
    };
    auto storeB = [&](int buf, const bf16x8 (&w)[2]) {
        *(bf16x8*)&Bs[buf][br][bh * 16]     = w[0];
        *(bf16x8*)&Bs[buf][br][bh * 16 + 8] = w[1];
    };
    auto mfmaTile = [&](int buf, int kt) {
        bf16x8 a = cheb_frag(hreg[kt]);
#pragma unroll
        for (int nt = 0; nt < 8; nt++) {
            bf16x8 b = *(const bf16x8*)&Bs[buf][nt * 16 + l16][quad * 8];
            acc[nt] = __builtin_amdgcn_mfma_f32_16x16x32_bf16(a, b, acc[nt], 0, 0, 0);
        }
    };

    bf16x8 wa[2], wb[2];
    loadB(0, wa);
    for (int kt = 0; kt < 16; kt += 2) {
        storeB(0, wa);
        loadB(kt + 1, wb);
        __syncthreads();
        mfmaTile(0, kt);
        storeB(1, wb);
        if (kt + 2 < 16) loadB(kt + 2, wa);
        __syncthreads();
        mfmaTile(1, kt + 1);
    }

    {
        int mrow = n0 + wave * 16 + quad * 4;
#pragma unroll
        for (int r = 0; r < 4; r++) {
            int n = mrow + r;
            if (n < N_NODES) {
#pragma unroll
                for (int nt = 0; nt < 8; nt++)
                    out[(long)n * HID + nt * 16 + l16] = (unsigned short)f2bf(acc[nt][r]);
            }
        }
    }
}

// ---------------------------------------------------------------------------
// MFMA GEMM 3 (layer 1 + W_out folded): z = Basis(h) @ C2W  [N x 512]@[512 x 16]
// B LDS-resident; A in registers; one barrier total.
// ---------------------------------------------------------------------------
__global__ __launch_bounds__(256, 4) void cheb16_gemm(const unsigned short* __restrict__ h,
                                                      const unsigned short* __restrict__ C2W,
                                                      float* __restrict__ z) {
    __shared__ __align__(16) short Bs16[16][520];
    const int tid  = threadIdx.x;
    const int lane = tid & 63;
    const int wave = tid >> 6;
    const int quad = lane >> 4;
    const int l16  = lane & 15;
    const int n0   = blockIdx.x * 64;

    {
        int o16 = tid >> 4;
        int seg = tid & 15;
        *(bf16x8*)&Bs16[o16][seg * 32]      = *(const bf16x8*)&C2W[o16 * 512 + seg * 32];
        *(bf16x8*)&Bs16[o16][seg * 32 + 8]  = *(const bf16x8*)&C2W[o16 * 512 + seg * 32 + 8];
        *(bf16x8*)&Bs16[o16][seg * 32 + 16] = *(const bf16x8*)&C2W[o16 * 512 + seg * 32 + 16];
        *(bf16x8*)&Bs16[o16][seg * 32 + 24] = *(const bf16x8*)&C2W[o16 * 512 + seg * 32 + 24];
    }

    int row = n0 + wave * 16 + l16; if (row >= N_NODES) row = N_NODES - 1;
    const unsigned short* __restrict__ hrow = h + (long)row * HID;

    unsigned hreg[16];
#pragma unroll
    for (int kt = 0; kt < 16; kt++)
        hreg[kt] = *(const unsigned*)(hrow + kt * 8 + quad * 2);

    f32x4 acc;
#pragma unroll
    for (int r = 0; r < 4; r++) acc[r] = 0.f;

    __syncthreads();   // B ready; the only barrier

#pragma unroll
    for (int kt = 0; kt < 16; kt++) {
        bf16x8 a = cheb_frag(hreg[kt]);
        bf16x8 b = *(const bf16x8*)&Bs16[l16][kt * 32 + quad * 8];
        acc = __builtin_amdgcn_mfma_f32_16x16x32_bf16(a, b, acc, 0, 0, 0);
    }

    {
        int mrow = n0 + wave * 16 + quad * 4;
#pragma unroll
        for (int r = 0; r < 4; r++) {
            int n = mrow + r;
            if (n < N_NODES) z[n * 16 + l16] = acc[r];
        }
    }
}

// ---------------------------------------------------------------------------
// SpMM gather (128-wide bf16, ROW-major h): wave/row; 16 lanes x uint4 per
// edge, 4 edges/instr, unrolled x2. Row bounds via row_start + row_cnt.
// ---------------------------------------------------------------------------
__global__ __launch_bounds__(256) void spmm_gather(const int* __restrict__ row_start,
                                                   const int* __restrict__ row_cnt,
                                                   const int* __restrict__ col_sorted,
                                                   const unsigned short* __restrict__ h,
                                                   unsigned short* __restrict__ out) {
    const int wid  = (blockIdx.x * 256 + threadIdx.x) >> 6;   // row
    const int lane = threadIdx.x & 63;
    const int sub  = lane >> 4;        // edge slot 0..3
    const int fl   = lane & 15;        // 16-byte feature slice 0..15
    if (wid >= N_NODES) return;
    const int s = row_start[wid];
    const int e = s + row_cnt[wid];
    const uint4* __restrict__ h4 = (const uint4*)h;   // one row = 16 uint4

    float a[8], b[8];
#pragma unroll
    for (int q = 0; q < 8; q++) { a[q] = 0.f; b[q] = 0.f; }

    int j = s;
    for (; j + 8 <= e; j += 8) {
        int c0 = col_sorted[j + sub];
        int c1 = col_sorted[j + 4 + sub];
        uint4 u0 = h4[c0 * 16 + fl];
        uint4 u1 = h4[c1 * 16 + fl];
        a[0] += bf_lo(u0.x); a[1] += bf_hi(u0.x);
        a[2] += bf_lo(u0.y); a[3] += bf_hi(u0.y);
        a[4] += bf_lo(u0.z); a[5] += bf_hi(u0.z);
        a[6] += bf_lo(u0.w); a[7] += bf_hi(u0.w);
        b[0] += bf_lo(u1.x); b[1] += bf_hi(u1.x);
        b[2] += bf_lo(u1.y); b[3] += bf_hi(u1.y);
        b[4] += bf_lo(u1.z); b[5] += bf_hi(u1.z);
        b[6] += bf_lo(u1.w); b[7] += bf_hi(u1.w);
    }
    for (; j < e; j += 4) {
        int idx = j + sub;
        float m = (idx < e) ? 1.f : 0.f;
        int ci = (idx < e) ? idx : (e - 1);
        int c = col_sorted[ci];
        uint4 u = h4[c * 16 + fl];
        a[0] = fmaf(m, bf_lo(u.x), a[0]); a[1] = fmaf(m, bf_hi(u.x), a[1]);
        a[2] = fmaf(m, bf_lo(u.y), a[2]); a[3] = fmaf(m, bf_hi(u.y), a[3]);
        a[4] = fmaf(m, bf_lo(u.z), a[4]); a[5] = fmaf(m, bf_hi(u.z), a[5]);
        a[6] = fmaf(m, bf_lo(u.w), a[6]); a[7] = fmaf(m, bf_hi(u.w), a[7]);
    }
#pragma unroll
    for (int q = 0; q < 8; q++) a[q] += b[q];
#pragma unroll
    for (int q = 0; q < 8; q++) {
        a[q] += __shfl_xor(a[q], 16);
        a[q] += __shfl_xor(a[q], 32);
    }
    if (sub == 0) {
        unsigned w0 = (unsigned)(unsigned short)f2bf(a[0]) | ((unsigned)(unsigned short)f2bf(a[1]) << 16);
        unsigned w1 = (unsigned)(unsigned short)f2bf(a[2]) | ((unsigned)(unsigned short)f2bf(a[3]) << 16);
        unsigned w2 = (unsigned)(unsigned short)f2bf(a[4]) | ((unsigned)(unsigned short)f2bf(a[5]) << 16);
        unsigned w3 = (unsigned)(unsigned short)f2bf(a[6]) | ((unsigned)(unsigned short)f2bf(a[7]) << 16);
        uint4 pw; pw.x = w0; pw.y = w1; pw.z = w2; pw.w = w3;
        ((uint4*)out)[wid * 16 + fl] = pw;
    }
}

// ---------------------------------------------------------------------------
// Final spmm (16-wide f32) + log_softmax fused; bounds via row_start+row_cnt.
// ---------------------------------------------------------------------------
__global__ __launch_bounds__(256) void spmm_out(const int* __restrict__ row_start,
                                                const int* __restrict__ row_cnt,
                                                const int* __restrict__ col_sorted,
                                                const float* __restrict__ z,
                                                float* __restrict__ out) {
    const int wid  = (blockIdx.x * 256 + threadIdx.x) >> 6;
    const int lane = threadIdx.x & 63;
    const int sub  = lane >> 4;
    const int fl   = lane & 15;
    if (wid >= N_NODES) return;
    const int s = row_start[wid];
    const int e = s + row_cnt[wid];

    float a0 = 0.f, a1 = 0.f;
    int j = s;
    for (; j + 8 <= e; j += 8) {
        int c0 = col_sorted[j + sub];
        int c1 = col_sorted[j + 4 + sub];
        a0 += z[c0 * 16 + fl];
        a1 += z[c1 * 16 + fl];
    }
    for (; j < e; j += 4) {
        int idx = j + sub;
        float m = (idx < e) ? 1.f : 0.f;
        int ci = (idx < e) ? idx : (e - 1);
        a0 = fmaf(m, z[col_sorted[ci] * 16 + fl], a0);
    }
    float v = a0 + a1;
    v += __shfl_xor(v, 16);
    v += __shfl_xor(v, 32);
    float mx = v;
#pragma unroll
    for (int m = 8; m >= 1; m >>= 1) mx = fmaxf(mx, __shfl_xor(mx, m));
    float ex = expf(v - mx);
    float se = ex;
#pragma unroll
    for (int m = 8; m >= 1; m >>= 1) se += __shfl_xor(se, m);
    if (sub == 0) out[wid * 16 + fl] = v - mx - logf(se);
}

// ---------------------------------------------------------------------------

extern "C" void kernel_launch(void* const* d_in, const int* in_sizes, int n_in,
                              void* d_out, int out_size, void* d_ws, size_t ws_size,
                              hipStream_t stream) {
    const float* x     = (const float*)d_in[0];
    const int*   ei    = (const int*)d_in[1];
    const float* W_in  = (const float*)d_in[2];
    const float* cheb  = (const float*)d_in[3];
    const float* W_out = (const float*)d_in[4];
    float* out = (float*)d_out;

    char* p = (char*)d_ws;
    unsigned short* hA   = (unsigned short*)p; p += (size_t)N_NODES * HID * 2;   // 25.6 MB
    unsigned short* hB   = (unsigned short*)p; p += (size_t)N_NODES * HID * 2;   // 25.6 MB
    int*   col_sorted    = (int*)p;            p += (size_t)N_EDGES * 4;         // 6.4 MB
    unsigned short* Bmat = (unsigned short*)p; p += (size_t)HID * KDIM * 2;      // 128 KB (layer-0)
    unsigned short* Wmat = (unsigned short*)p; p += (size_t)HID * KDIM * 2;      // 128 KB
    unsigned short* C2W  = (unsigned short*)p; p += (size_t)16 * KDIM * 2;       // 16 KB
    float* zbuf          = (float*)p;          p += (size_t)N_NODES * 16 * 4;    // 6.4 MB
    int*   row_start     = (int*)p;            p += (size_t)N_NODES * 4;         // 400 KB
    int*   row_cnt       = (int*)p;            p += (size_t)N_NODES * 4;         // 400 KB
    int*   bcnt          = (int*)p;            p += (size_t)(NB * 16 + 16) * 4;  // 50 KB + gctr slot

    int* gctr = bcnt + NB * 16;   // zeroed by the same memset

    // bucket buffer aliases hB (dead until spmm1 writes it; prep's gemm
    // section writes hA only, so bin ∥ gemm is safe)
    unsigned* bbuf = (unsigned*)hB;

    const int nblk_prep = NG_GEMM + NG_BIN;            // 3907 (512-thread blocks)
    const int nblk_gemm = (N_NODES + 63) / 64;         // 1563
    const int nblk_spmm = (N_NODES + 3) / 4;           // 25000

    hipMemsetAsync(bcnt, 0, (size_t)(NB * 16 + 16) * 4, stream);

    repack_all<<<544, 256, 0, stream>>>(cheb, W_in, W_out, Bmat, Wmat, C2W);

    // gemm_xw ∥ bin in one launch (disjoint outputs)
    prep_kernel<<<nblk_prep, 512, 0, stream>>>(x, ei, Wmat, hA, bcnt, bbuf);
    place_kernel<<<NB, 256, 0, stream>>>(bbuf, bcnt, gctr, row_start, row_cnt, col_sorted);

    spmm_gather<<<nblk_spmm, 256, 0, stream>>>(row_start, row_cnt, col_sorted, hA, hB);

    cheb_gemm<<<nblk_gemm, 256, 0, stream>>>(hB, Bmat, hA);                    // layer 0
    spmm_gather<<<nblk_spmm, 256, 0, stream>>>(row_start, row_cnt, col_sorted, hA, hB);

    cheb16_gemm<<<nblk_gemm, 256, 0, stream>>>(hB, C2W, zbuf);                 // layer 1 + W_out
    spmm_out<<<nblk_spmm, 256, 0, stream>>>(row_start, row_cnt, col_sorted, zbuf, out); // spmm + lsm
}

// Round 25
// 603.463 us; speedup vs baseline: 1.1499x; 1.0192x over previous
//
#include <hip/hip_runtime.h>
#include <hip/hip_bf16.h>

#define N_NODES 100000
#define N_EDGES 1600000
#define IN_DIM  500
#define HID     128
#define KDIM    512   // HID * (DEG+1)
#define NB      782   // ceil(N_NODES/128) buckets
#define BCAP_S  512   // per-slice bucket capacity (expected 256, >15 sigma)

#define NG_GEMM 782   // gemm_xw blocks (128-row tiles, 512 threads)
#define NG_BIN  3125  // bin blocks (512 edges each)

typedef __attribute__((ext_vector_type(8))) short bf16x8;
typedef __attribute__((ext_vector_type(4))) float f32x4;

__device__ inline short f2bf(float x) {
    union { float f; unsigned u; } v; v.f = x;
    unsigned r = (v.u + 0x7FFFu + ((v.u >> 16) & 1u)) >> 16;  // RNE
    return (short)r;
}
__device__ inline float bf_lo(unsigned u) { union { unsigned u; float f; } v; v.u = u << 16; return v.f; }
__device__ inline float bf_hi(unsigned u) { union { unsigned u; float f; } v; v.u = u & 0xFFFF0000u; return v.f; }

// Chebyshev basis from 2 packed bf16 features -> 8 bf16 A-fragment
__device__ inline bf16x8 cheb_frag(unsigned v) {
    float hx[2] = {bf_lo(v), bf_hi(v)};
    short t[8];
#pragma unroll
    for (int q = 0; q < 2; q++) {
        float xx = fminf(fmaxf(hx[q], -15.f), 15.f);
        float e  = __expf(2.f * xx);
        float tt = (e - 1.f) / (e + 1.f);     // tanh
        float T2 = 2.f * tt * tt - 1.f;
        float T3 = 2.f * tt * T2 - tt;
        t[q * 4 + 0] = (short)0x3F80;         // bf16(1.0)
        t[q * 4 + 1] = f2bf(tt);
        t[q * 4 + 2] = f2bf(T2);
        t[q * 4 + 3] = f2bf(T3);
    }
    return *(bf16x8*)&t[0];
}

// ---------------------------------------------------------------------------
// Merged repacks, launched BEFORE prep (prep's gemm reads Wmat).
// ---------------------------------------------------------------------------
__global__ __launch_bounds__(256) void repack_all(const float* __restrict__ cheb,
                                                  const float* __restrict__ W,
                                                  const float* __restrict__ Wout,
                                                  unsigned short* __restrict__ Bmat,
                                                  unsigned short* __restrict__ Wmat,
                                                  unsigned short* __restrict__ C2W) {
    const int b = blockIdx.x;
    if (b < 256) {
        int idx = b * 256 + threadIdx.x;       // < 128*512
        int o = idx >> 9;
        int k = idx & 511;
        int i = k >> 2;
        int d = k & 3;
        Bmat[idx] = (unsigned short)f2bf(cheb[i * 512 + o * 4 + d]);
    } else if (b < 512) {
        int idx = (b - 256) * 256 + threadIdx.x;
        int o = idx >> 9;
        int k = idx & 511;
        Wmat[idx] = (k < IN_DIM) ? (unsigned short)f2bf(W[k * HID + o]) : 0;
    } else {
        int idx = (b - 512) * 256 + threadIdx.x;   // < 16*512
        int o16 = idx >> 9;
        int k   = idx & 511;
        const float* cb = cheb + 65536 + (k >> 2) * 512 + (k & 3);
        float s = 0.f;
#pragma unroll 4
        for (int o = 0; o < 128; o++) s += cb[o * 4] * Wout[o * 16 + o16];
        C2W[o16 * 512 + k] = (unsigned short)f2bf(s);
    }
}

// ---------------------------------------------------------------------------
// PREP super-kernel, 512 threads: blocks [0,NG_GEMM) run gemm_xw on 128-row
// tiles (8 waves share ONE 20.5KB B-dbuf, r21 structure = best measured);
// remainder runs edge binning, now XCD-SLICED: slice = blockIdx&7 tracks the
// round-robin block->XCD map, so each bucket sub-segment is written by ONE
// XCD and adjacent 4B writes merge into full 64B lines in that XCD's L2
// (r21 PMC: WRITE_SIZE 108MB vs ~32MB payload = scatter amplification).
// ---------------------------------------------------------------------------
__global__ __launch_bounds__(512, 2) void prep_kernel(const float* __restrict__ x,
                                                      const int* __restrict__ ei,
                                                      const unsigned short* __restrict__ Wmat,
                                                      unsigned short* __restrict__ hA,
                                                      int* __restrict__ bcnt,
                                                      unsigned* __restrict__ bbuf) {
    __shared__ __align__(16) short Bs[2][128][40];   // 20.5 KB, shared by 8 waves
    const int tid = threadIdx.x;

    if (blockIdx.x < NG_GEMM) {
        const int lane = tid & 63;
        const int wave = tid >> 6;     // 0..7
        const int quad = lane >> 4;
        const int l16  = lane & 15;
        const int n0   = blockIdx.x * 128;
        const int br   = tid >> 2;     // B row 0..127
        const int bh   = tid & 3;      // 8-short segment

        int row = n0 + wave * 16 + l16; if (row >= N_NODES) row = N_NODES - 1;
        const float* __restrict__ xrow = x + (long)row * IN_DIM;

        f32x4 acc[8];
#pragma unroll
        for (int nt = 0; nt < 8; nt++)
#pragma unroll
            for (int r = 0; r < 4; r++) acc[nt][r] = 0.f;

        auto loadA = [&](int kt, float (&v)[8]) {
            const int kb = kt * 32 + quad * 8;
            if (kb + 8 <= IN_DIM) {
                const float4* s4 = (const float4*)(xrow + kb);
                float4 a0 = s4[0], a1 = s4[1];
                v[0]=a0.x; v[1]=a0.y; v[2]=a0.z; v[3]=a0.w;
                v[4]=a1.x; v[5]=a1.y; v[6]=a1.z; v[7]=a1.w;
            } else {
#pragma unroll
                for (int q = 0; q < 8; q++) v[q] = (kb + q < IN_DIM) ? xrow[kb + q] : 0.f;
            }
        };
        auto loadB = [&](int kt, bf16x8& w) {
            w = *(const bf16x8*)&Wmat[br * 512 + kt * 32 + bh * 8];
        };
        auto storeB = [&](int buf, const bf16x8& w) {
            *(bf16x8*)&Bs[buf][br][bh * 8] = w;
        };
        auto mfmaTile = [&](int buf, const float (&v)[8]) {
            short t[8];
#pragma unroll
            for (int q = 0; q < 8; q++) t[q] = f2bf(v[q]);
            bf16x8 a = *(bf16x8*)&t[0];
#pragma unroll
            for (int nt = 0; nt < 8; nt++) {
                bf16x8 b = *(const bf16x8*)&Bs[buf][nt * 16 + l16][quad * 8];
                acc[nt] = __builtin_amdgcn_mfma_f32_16x16x32_bf16(a, b, acc[nt], 0, 0, 0);
            }
        };

        float  A[4][8];               // 4-deep ring; all indices compile-time
        bf16x8 wa, wb;
        loadA(0, A[0]);
        loadA(1, A[1]);
        loadB(0, wa);
#pragma unroll
        for (int kt = 0; kt < 16; kt += 2) {
            storeB(0, wa);
            loadB(kt + 1, wb);
            if (kt + 2 < 16) loadA(kt + 2, A[(kt + 2) & 3]);
            __syncthreads();
            mfmaTile(0, A[kt & 3]);
            storeB(1, wb);
            if (kt + 3 < 16) loadA(kt + 3, A[(kt + 3) & 3]);
            if (kt + 2 < 16) loadB(kt + 2, wa);
            __syncthreads();
            mfmaTile(1, A[(kt + 1) & 3]);
        }

        int mrow = n0 + wave * 16 + quad * 4;
#pragma unroll
        for (int r = 0; r < 4; r++) {
            int n = mrow + r;
            if (n < N_NODES) {
#pragma unroll
                for (int nt = 0; nt < 8; nt++)
                    hA[(long)n * HID + nt * 16 + l16] = (unsigned short)f2bf(acc[nt][r]);
            }
        }
    } else {
        // ---- bin: bucket each edge by row>>7, XCD-sliced ------------------
        int e = (blockIdx.x - NG_GEMM) * 512 + tid;
        if (e < N_EDGES) {
            int r = ei[e];
            int c = ei[N_EDGES + e];
            int b = r >> 7;
            int s = blockIdx.x & 7;                        // ~XCD id
            int p = atomicAdd(&bcnt[b * 128 + s * 16], 1); // 64B-strided counters
            if (p < BCAP_S)
                bbuf[((b << 3) + s) * BCAP_S + p] = ((unsigned)(r & 127) << 17) | (unsigned)c;
        }
    }
}

// ---------------------------------------------------------------------------
// place: per-bucket local histogram + scan over the 8 XCD slices; bucket's
// global base claimed via ONE atomic ticket. Rows get row_start+row_cnt.
// ---------------------------------------------------------------------------
__global__ __launch_bounds__(256) void place_kernel(const unsigned* __restrict__ buf,
                                                    const int* __restrict__ bcnt,
                                                    int* __restrict__ gctr,
                                                    int* __restrict__ row_start,
                                                    int* __restrict__ row_cnt,
                                                    int* __restrict__ col_sorted) {
    __shared__ int hist[128];
    __shared__ int scan[128];
    __shared__ int cur[128];
    __shared__ int base_s;
    const int b = blockIdx.x, tid = threadIdx.x;
    if (tid < 128) hist[tid] = 0;
    __syncthreads();
#pragma unroll
    for (int s = 0; s < 8; s++) {
        int cs = bcnt[b * 128 + s * 16]; if (cs > BCAP_S) cs = BCAP_S;
        for (int i = tid; i < cs; i += 256)
            atomicAdd(&hist[buf[((b << 3) + s) * BCAP_S + i] >> 17], 1);
    }
    __syncthreads();
    if (tid < 128) scan[tid] = hist[tid];
    __syncthreads();
    for (int off = 1; off < 128; off <<= 1) {
        int t = (tid < 128 && tid >= off) ? scan[tid - off] : 0;
        __syncthreads();
        if (tid < 128) scan[tid] += t;
        __syncthreads();
    }
    if (tid == 0) base_s = atomicAdd(gctr, scan[127]);   // ticket for this bucket
    __syncthreads();
    const int base = base_s;
    if (tid < 128) {
        int excl = scan[tid] - hist[tid] + base;
        cur[tid] = excl;
        int r = b * 128 + tid;
        if (r < N_NODES) { row_start[r] = excl; row_cnt[r] = hist[tid]; }
    }
    __syncthreads();
#pragma unroll
    for (int s = 0; s < 8; s++) {
        int cs = bcnt[b * 128 + s * 16]; if (cs > BCAP_S) cs = BCAP_S;
        for (int i = tid; i < cs; i += 256) {
            unsigned u = buf[((b << 3) + s) * BCAP_S + i];
            int rl = (int)(u >> 17);
            int c  = (int)(u & 0x1FFFFu);
            int pos = atomicAdd(&cur[rl], 1);
            col_sorted[pos] = c;
        }
    }
}

// ---------------------------------------------------------------------------
// MFMA GEMM 2 (layer 0): out = Basis(h) @ C1  [N x 512]@[512 x 128]
// A via upfront register preload + per-kt basis. B dbuf'd.
// ---------------------------------------------------------------------------
__global__ __launch_bounds__(256, 4) void cheb_gemm(const unsigned short* __restrict__ h,
                                                    const unsigned short* __restrict__ Bmat,
                                                    unsigned short* __restrict__ out) {
    __shared__ __align__(16) short Bs[2][128][40];
    const int tid  = threadIdx.x;
    const int lane = tid & 63;
    const int wave = tid >> 6;
    const int quad = lane >> 4;
    const int l16  = lane & 15;
    const int n0   = blockIdx.x * 64;
    const int br   = tid >> 1;
    const int bh   = tid & 1;

    int row = n0 + wave * 16 + l16; if (row >= N_NODES) row = N_NODES - 1;
    const unsigned short* __restrict__ hrow = h + (long)row * HID;

    unsigned hreg[16];
#pragma unroll
    for (int kt = 0; kt < 16; kt++)
        hreg[kt] = *(const unsigned*)(hrow + kt * 8 + quad * 2);

    f32x4 acc[8];
#pragma unroll
    for (int nt = 0; nt < 8; nt++)
#pragma unroll
        for (int r = 0; r < 4; r++) acc[nt][r] = 0.f;

    auto loadB = [&](int kt, bf16x8 (&w)[2]) {
        w[0] = *(const bf16x8*)&Bmat[br * 512 + kt * 32 + bh * 16];
        w[1] = *(const bf16x8*)&Bmat[br * 512 + kt * 32 + bh * 16 + 8];
    };
    auto storeB = [&](int buf, const bf16x8 (&w)[2]) {
        *(bf16x8*)&Bs[buf][br][bh * 16]     = w[0];
        *(bf16x8*)&Bs[buf][br][bh * 16 + 8] = w[1];
    };
    auto mfmaTile = [&](int buf, int kt) {
        bf16x8 a = cheb_frag(hreg[kt]);
#pragma unroll
        for (int nt = 0; nt < 8; nt++) {
            bf16x8 b = *(const bf16x8*)&Bs[buf][nt * 16 + l16][quad * 8];
            acc[nt] = __builtin_amdgcn_mfma_f32_16x16x32_bf16(a, b, acc[nt], 0, 0, 0);
        }
    };

    bf16x8 wa[2], wb[2];
    loadB(0, wa);
    for (int kt = 0; kt < 16; kt += 2) {
        storeB(0, wa);
        loadB(kt + 1, wb);
        __syncthreads();
        mfmaTile(0, kt);
        storeB(1, wb);
        if (kt + 2 < 16) loadB(kt + 2, wa);
        __syncthreads();
        mfmaTile(1, kt + 1);
    }

    {
        int mrow = n0 + wave * 16 + quad * 4;
#pragma unroll
        for (int r = 0; r < 4; r++) {
            int n = mrow + r;
            if (n < N_NODES) {
#pragma unroll
                for (int nt = 0; nt < 8; nt++)
                    out[(long)n * HID + nt * 16 + l16] = (unsigned short)f2bf(acc[nt][r]);
            }
        }
    }
}

// ---------------------------------------------------------------------------
// MFMA GEMM 3 (layer 1 + W_out folded): z = Basis(h) @ C2W  [N x 512]@[512 x 16]
// B LDS-resident; A in registers; one barrier total.
// ---------------------------------------------------------------------------
__global__ __launch_bounds__(256, 4) void cheb16_gemm(const unsigned short* __restrict__ h,
                                                      const unsigned short* __restrict__ C2W,
                                                      float* __restrict__ z) {
    __shared__ __align__(16) short Bs16[16][520];
    const int tid  = threadIdx.x;
    const int lane = tid & 63;
    const int wave = tid >> 6;
    const int quad = lane >> 4;
    const int l16  = lane & 15;
    const int n0   = blockIdx.x * 64;

    {
        int o16 = tid >> 4;
        int seg = tid & 15;
        *(bf16x8*)&Bs16[o16][seg * 32]      = *(const bf16x8*)&C2W[o16 * 512 + seg * 32];
        *(bf16x8*)&Bs16[o16][seg * 32 + 8]  = *(const bf16x8*)&C2W[o16 * 512 + seg * 32 + 8];
        *(bf16x8*)&Bs16[o16][seg * 32 + 16] = *(const bf16x8*)&C2W[o16 * 512 + seg * 32 + 16];
        *(bf16x8*)&Bs16[o16][seg * 32 + 24] = *(const bf16x8*)&C2W[o16 * 512 + seg * 32 + 24];
    }

    int row = n0 + wave * 16 + l16; if (row >= N_NODES) row = N_NODES - 1;
    const unsigned short* __restrict__ hrow = h + (long)row * HID;

    unsigned hreg[16];
#pragma unroll
    for (int kt = 0; kt < 16; kt++)
        hreg[kt] = *(const unsigned*)(hrow + kt * 8 + quad * 2);

    f32x4 acc;
#pragma unroll
    for (int r = 0; r < 4; r++) acc[r] = 0.f;

    __syncthreads();   // B ready; the only barrier

#pragma unroll
    for (int kt = 0; kt < 16; kt++) {
        bf16x8 a = cheb_frag(hreg[kt]);
        bf16x8 b = *(const bf16x8*)&Bs16[l16][kt * 32 + quad * 8];
        acc = __builtin_amdgcn_mfma_f32_16x16x32_bf16(a, b, acc, 0, 0, 0);
    }

    {
        int mrow = n0 + wave * 16 + quad * 4;
#pragma unroll
        for (int r = 0; r < 4; r++) {
            int n = mrow + r;
            if (n < N_NODES) z[n * 16 + l16] = acc[r];
        }
    }
}

// ---------------------------------------------------------------------------
// SpMM gather (128-wide bf16, ROW-major h): wave/row; 16 lanes x uint4 per
// edge, 4 edges/instr, unrolled x2. Row bounds via row_start + row_cnt.
// ---------------------------------------------------------------------------
__global__ __launch_bounds__(256) void spmm_gather(const int* __restrict__ row_start,
                                                   const int* __restrict__ row_cnt,
                                                   const int* __restrict__ col_sorted,
                                                   const unsigned short* __restrict__ h,
                                                   unsigned short* __restrict__ out) {
    const int wid  = (blockIdx.x * 256 + threadIdx.x) >> 6;   // row
    const int lane = threadIdx.x & 63;
    const int sub  = lane >> 4;        // edge slot 0..3
    const int fl   = lane & 15;        // 16-byte feature slice 0..15
    if (wid >= N_NODES) return;
    const int s = row_start[wid];
    const int e = s + row_cnt[wid];
    const uint4* __restrict__ h4 = (const uint4*)h;   // one row = 16 uint4

    float a[8], b[8];
#pragma unroll
    for (int q = 0; q < 8; q++) { a[q] = 0.f; b[q] = 0.f; }

    int j = s;
    for (; j + 8 <= e; j += 8) {
        int c0 = col_sorted[j + sub];
        int c1 = col_sorted[j + 4 + sub];
        uint4 u0 = h4[c0 * 16 + fl];
        uint4 u1 = h4[c1 * 16 + fl];
        a[0] += bf_lo(u0.x); a[1] += bf_hi(u0.x);
        a[2] += bf_lo(u0.y); a[3] += bf_hi(u0.y);
        a[4] += bf_lo(u0.z); a[5] += bf_hi(u0.z);
        a[6] += bf_lo(u0.w); a[7] += bf_hi(u0.w);
        b[0] += bf_lo(u1.x); b[1] += bf_hi(u1.x);
        b[2] += bf_lo(u1.y); b[3] += bf_hi(u1.y);
        b[4] += bf_lo(u1.z); b[5] += bf_hi(u1.z);
        b[6] += bf_lo(u1.w); b[7] += bf_hi(u1.w);
    }
    for (; j < e; j += 4) {
        int idx = j + sub;
        float m = (idx < e) ? 1.f : 0.f;
        int ci = (idx < e) ? idx : (e - 1);
        int c = col_sorted[ci];
        uint4 u = h4[c * 16 + fl];
        a[0] = fmaf(m, bf_lo(u.x), a[0]); a[1] = fmaf(m, bf_hi(u.x), a[1]);
        a[2] = fmaf(m, bf_lo(u.y), a[2]); a[3] = fmaf(m, bf_hi(u.y), a[3]);
        a[4] = fmaf(m, bf_lo(u.z), a[4]); a[5] = fmaf(m, bf_hi(u.z), a[5]);
        a[6] = fmaf(m, bf_lo(u.w), a[6]); a[7] = fmaf(m, bf_hi(u.w), a[7]);
    }
#pragma unroll
    for (int q = 0; q < 8; q++) a[q] += b[q];
#pragma unroll
    for (int q = 0; q < 8; q++) {
        a[q] += __shfl_xor(a[q], 16);
        a[q] += __shfl_xor(a[q], 32);
    }
    if (sub == 0) {
        unsigned w0 = (unsigned)(unsigned short)f2bf(a[0]) | ((unsigned)(unsigned short)f2bf(a[1]) << 16);
        unsigned w1 = (unsigned)(unsigned short)f2bf(a[2]) | ((unsigned)(unsigned short)f2bf(a[3]) << 16);
        unsigned w2 = (unsigned)(unsigned short)f2bf(a[4]) | ((unsigned)(unsigned short)f2bf(a[5]) << 16);
        unsigned w3 = (unsigned)(unsigned short)f2bf(a[6]) | ((unsigned)(unsigned short)f2bf(a[7]) << 16);
        uint4 pw; pw.x = w0; pw.y = w1; pw.z = w2; pw.w = w3;
        ((uint4*)out)[wid * 16 + fl] = pw;
    }
}

// ---------------------------------------------------------------------------
// Final spmm (16-wide f32) + log_softmax fused; bounds via row_start+row_cnt.
// ---------------------------------------------------------------------------
__global__ __launch_bounds__(256) void spmm_out(const int* __restrict__ row_start,
                                                const int* __restrict__ row_cnt,
                                                const int* __restrict__ col_sorted,
                                                const float* __restrict__ z,
                                                float* __restrict__ out) {
    const int wid  = (blockIdx.x * 256 + threadIdx.x) >> 6;
    const int lane = threadIdx.x & 63;
    const int sub  = lane >> 4;
    const int fl   = lane & 15;
    if (wid >= N_NODES) return;
    const int s = row_start[wid];
    const int e = s + row_cnt[wid];

    float a0 = 0.f, a1 = 0.f;
    int j = s;
    for (; j + 8 <= e; j += 8) {
        int c0 = col_sorted[j + sub];
        int c1 = col_sorted[j + 4 + sub];
        a0 += z[c0 * 16 + fl];
        a1 += z[c1 * 16 + fl];
    }
    for (; j < e; j += 4) {
        int idx = j + sub;
        float m = (idx < e) ? 1.f : 0.f;
        int ci = (idx < e) ? idx : (e - 1);
        a0 = fmaf(m, z[col_sorted[ci] * 16 + fl], a0);
    }
    float v = a0 + a1;
    v += __shfl_xor(v, 16);
    v += __shfl_xor(v, 32);
    float mx = v;
#pragma unroll
    for (int m = 8; m >= 1; m >>= 1) mx = fmaxf(mx, __shfl_xor(mx, m));
    float ex = expf(v - mx);
    float se = ex;
#pragma unroll
    for (int m = 8; m >= 1; m >>= 1) se += __shfl_xor(se, m);
    if (sub == 0) out[wid * 16 + fl] = v - mx - logf(se);
}

// ---------------------------------------------------------------------------

extern "C" void kernel_launch(void* const* d_in, const int* in_sizes, int n_in,
                              void* d_out, int out_size, void* d_ws, size_t ws_size,
                              hipStream_t stream) {
    const float* x     = (const float*)d_in[0];
    const int*   ei    = (const int*)d_in[1];
    const float* W_in  = (const float*)d_in[2];
    const float* cheb  = (const float*)d_in[3];
    const float* W_out = (const float*)d_in[4];
    float* out = (float*)d_out;

    char* p = (char*)d_ws;
    unsigned short* hA   = (unsigned short*)p; p += (size_t)N_NODES * HID * 2;   // 25.6 MB
    unsigned short* hB   = (unsigned short*)p; p += (size_t)N_NODES * HID * 2;   // 25.6 MB
    int*   col_sorted    = (int*)p;            p += (size_t)N_EDGES * 4;         // 6.4 MB
    unsigned short* Bmat = (unsigned short*)p; p += (size_t)HID * KDIM * 2;      // 128 KB (layer-0)
    unsigned short* Wmat = (unsigned short*)p; p += (size_t)HID * KDIM * 2;      // 128 KB
    unsigned short* C2W  = (unsigned short*)p; p += (size_t)16 * KDIM * 2;       // 16 KB
    float* zbuf          = (float*)p;          p += (size_t)N_NODES * 16 * 4;    // 6.4 MB
    int*   row_start     = (int*)p;            p += (size_t)N_NODES * 4;         // 400 KB
    int*   row_cnt       = (int*)p;            p += (size_t)N_NODES * 4;         // 400 KB
    int*   bcnt          = (int*)p;            p += (size_t)(NB * 128 + 16) * 4; // 400 KB + gctr slot

    int* gctr = bcnt + NB * 128;   // zeroed by the same memset

    // bucket buffer aliases hB (dead until spmm1 writes it; prep's gemm
    // section writes hA only, so bin ∥ gemm is safe).
    // NB*8*BCAP_S*4 = 12.8 MB < 25.6 MB.
    unsigned* bbuf = (unsigned*)hB;

    const int nblk_prep = NG_GEMM + NG_BIN;            // 3907 (512-thread blocks)
    const int nblk_gemm = (N_NODES + 63) / 64;         // 1563
    const int nblk_spmm = (N_NODES + 3) / 4;           // 25000

    hipMemsetAsync(bcnt, 0, (size_t)(NB * 128 + 16) * 4, stream);

    repack_all<<<544, 256, 0, stream>>>(cheb, W_in, W_out, Bmat, Wmat, C2W);

    // gemm_xw ∥ bin in one launch (disjoint outputs)
    prep_kernel<<<nblk_prep, 512, 0, stream>>>(x, ei, Wmat, hA, bcnt, bbuf);
    place_kernel<<<NB, 256, 0, stream>>>(bbuf, bcnt, gctr, row_start, row_cnt, col_sorted);

    spmm_gather<<<nblk_spmm, 256, 0, stream>>>(row_start, row_cnt, col_sorted, hA, hB);

    cheb_gemm<<<nblk_gemm, 256, 0, stream>>>(hB, Bmat, hA);                    // layer 0
    spmm_gather<<<nblk_spmm, 256, 0, stream>>>(row_start, row_cnt, col_sorted, hA, hB);

    cheb16_gemm<<<nblk_gemm, 256, 0, stream>>>(hB, C2W, zbuf);                 // layer 1 + W_out
    spmm_out<<<nblk_spmm, 256, 0, stream>>>(row_start, row_cnt, col_sorted, zbuf, out); // spmm + lsm
}